// Round 1
// baseline (4253.776 us; speedup 1.0000x reference)
//
#include <hip/hip_runtime.h>

#define NB 4096
#define LSEQ 45
#define DMODEL 128
#define DINNER 256
#define NSTATE 4
#define RNK 8

__device__ __forceinline__ float dot4(float4 a, float4 b) {
    return a.x*b.x + a.y*b.y + a.z*b.z + a.w*b.w;
}

__global__ __launch_bounds__(256, 2)
void mamba_fused_kernel(const float* __restrict__ x,        // B,L,DM
                        const int*   __restrict__ pad_mask, // B,L
                        const float* __restrict__ W_in,     // 2*DI, DM
                        const float* __restrict__ conv_w,   // DI,2
                        const float* __restrict__ conv_b,   // DI
                        const float* __restrict__ W_x,      // 16, DI
                        const float* __restrict__ W_dt,     // DI, RNK
                        const float* __restrict__ b_dt,     // DI
                        const float* __restrict__ A_log,    // DI, NSTATE
                        const float* __restrict__ Dvec,     // DI
                        const float* __restrict__ W_out,    // DM, DI
                        float* __restrict__ out)            // [NB*DM rep][NB*L*DM feat]
{
    const int b = blockIdx.x;
    const int t = threadIdx.x;

    __shared__ __align__(16) float s_buf[LSEQ*DINNER];   // xs[45][128] then u/y[45][256]
    __shared__ __align__(16) float s_xdbl[LSEQ*16];
    __shared__ float s_red[256];
    __shared__ float s_coff[LSEQ];
    __shared__ float s_csum;

    // ---- phase 1: stage x[b] into LDS ----
    const float* xb = x + (size_t)b*LSEQ*DMODEL;
    for (int i = t; i < LSEQ*DMODEL/4; i += 256)
        ((float4*)s_buf)[i] = ((const float4*)xb)[i];
    if (t < LSEQ) s_coff[t] = 1.0f - (float)pad_mask[b*LSEQ + t];
    __syncthreads();
    if (t == 0) {
        float cs = 0.f;
        for (int l = 0; l < LSEQ; ++l) cs += s_coff[l];
        s_csum = cs;
    }

    // ---- phase 2: xc[l] = x[l]·W_in[t], z[l] = x[l]·W_in[256+t] ----
    float accXC[LSEQ], accZ[LSEQ];
    #pragma unroll
    for (int l = 0; l < LSEQ; ++l) { accXC[l] = 0.f; accZ[l] = 0.f; }
    {
        const float* wxc = W_in + (size_t)t * DMODEL;
        const float* wz  = W_in + (size_t)(t + DINNER) * DMODEL;
        for (int kc = 0; kc < DMODEL; kc += 16) {
            const float4 wa0 = *(const float4*)(wxc + kc);
            const float4 wa1 = *(const float4*)(wxc + kc + 4);
            const float4 wa2 = *(const float4*)(wxc + kc + 8);
            const float4 wa3 = *(const float4*)(wxc + kc + 12);
            const float4 wb0 = *(const float4*)(wz + kc);
            const float4 wb1 = *(const float4*)(wz + kc + 4);
            const float4 wb2 = *(const float4*)(wz + kc + 8);
            const float4 wb3 = *(const float4*)(wz + kc + 12);
            #pragma unroll
            for (int l = 0; l < LSEQ; ++l) {
                const float4* xr = (const float4*)(s_buf + l*DMODEL + kc);
                const float4 x0 = xr[0], x1 = xr[1], x2 = xr[2], x3 = xr[3];
                accXC[l] += dot4(x0,wa0) + dot4(x1,wa1) + dot4(x2,wa2) + dot4(x3,wa3);
                accZ[l]  += dot4(x0,wb0) + dot4(x1,wb1) + dot4(x2,wb2) + dot4(x3,wb3);
            }
        }
    }

    // ---- phase 3: depthwise conv (2 taps) + SiLU ----
    const float cw0 = conv_w[2*t], cw1 = conv_w[2*t+1], cb = conv_b[t];
    float u_[LSEQ];
    #pragma unroll
    for (int l = 0; l < LSEQ; ++l) {
        float v = cb + accXC[l]*cw1 + (l ? accXC[l-1]*cw0 : 0.f);
        u_[l] = v / (1.f + expf(-v));
    }
    __syncthreads();               // everyone done reading xs
    #pragma unroll
    for (int l = 0; l < LSEQ; ++l) s_buf[l*DINNER + t] = u_[l];
    __syncthreads();

    // ---- phase 4: x_dbl[l][r] = u[l]·W_x[r] (45x16 outputs) ----
    for (int idx = t; idx < LSEQ*16; idx += 256) {
        const int l = idx >> 4, r = idx & 15;
        const float4* ur = (const float4*)(s_buf + l*DINNER);
        const float4* wr = (const float4*)(W_x + r*DINNER);
        float acc = 0.f;
        for (int j = 0; j < DINNER/4; ++j)
            acc += dot4(ur[j], wr[j]);
        s_xdbl[idx] = acc;
    }
    __syncthreads();

    // ---- phase 5: delta + selective scan (channel t, sequential over l) ----
    float wdt[RNK];
    #pragma unroll
    for (int r = 0; r < RNK; ++r) wdt[r] = W_dt[t*RNK + r];
    const float bdt = b_dt[t];
    float Av[NSTATE];
    #pragma unroll
    for (int n = 0; n < NSTATE; ++n) Av[n] = -expf(A_log[t*NSTATE + n]);
    const float Dv = Dvec[t];
    float h0=0.f, h1=0.f, h2=0.f, h3=0.f;
    #pragma unroll
    for (int l = 0; l < LSEQ; ++l) {
        const float* xd = s_xdbl + l*16;
        float dtv = bdt;
        #pragma unroll
        for (int r = 0; r < RNK; ++r) dtv += xd[r]*wdt[r];
        const float delta = (dtv > 20.f) ? dtv : log1pf(expf(dtv));
        const float ue = s_buf[l*DINNER + t];
        const float du = delta * ue;
        h0 = expf(delta*Av[0])*h0 + du*xd[8];
        h1 = expf(delta*Av[1])*h1 + du*xd[9];
        h2 = expf(delta*Av[2])*h2 + du*xd[10];
        h3 = expf(delta*Av[3])*h3 + du*xd[11];
        float y = h0*xd[12] + h1*xd[13] + h2*xd[14] + h3*xd[15] + ue*Dv;
        const float zv = accZ[l];
        y *= zv / (1.f + expf(-zv));
        s_buf[l*DINNER + t] = y;     // in-place: only thread t touches this slot
    }
    __syncthreads();

    // ---- phase 6: feat[l][d] = y[l]·W_out[d]; fused masked-mean for rep ----
    const int d = t & 127;
    const int half = t >> 7;
    float accF[23];
    #pragma unroll
    for (int i = 0; i < 23; ++i) accF[i] = 0.f;
    const float* wor = W_out + d*DINNER;
    for (int ec = 0; ec < DINNER; ec += 16) {
        const float4 w0 = *(const float4*)(wor + ec);
        const float4 w1 = *(const float4*)(wor + ec + 4);
        const float4 w2 = *(const float4*)(wor + ec + 8);
        const float4 w3 = *(const float4*)(wor + ec + 12);
        #pragma unroll
        for (int li = 0; li < 23; ++li) {
            const int l = 2*li + half;
            if (l < LSEQ) {
                const float4* yr = (const float4*)(s_buf + l*DINNER + ec);
                accF[li] += dot4(yr[0],w0) + dot4(yr[1],w1)
                          + dot4(yr[2],w2) + dot4(yr[3],w3);
            }
        }
    }
    float* featb = out + (size_t)NB*DMODEL + (size_t)b*LSEQ*DMODEL;
    float racc = 0.f;
    #pragma unroll
    for (int li = 0; li < 23; ++li) {
        const int l = 2*li + half;
        if (l < LSEQ) {
            featb[l*DMODEL + d] = accF[li];
            racc += s_coff[l] * accF[li];
        }
    }
    s_red[t] = racc;
    __syncthreads();
    if (t < DMODEL)
        out[(size_t)b*DMODEL + t] = (s_red[t] + s_red[t + DMODEL]) / s_csum;
}

extern "C" void kernel_launch(void* const* d_in, const int* in_sizes, int n_in,
                              void* d_out, int out_size, void* d_ws, size_t ws_size,
                              hipStream_t stream) {
    mamba_fused_kernel<<<NB, 256, 0, stream>>>(
        (const float*)d_in[0], (const int*)d_in[1], (const float*)d_in[2],
        (const float*)d_in[3], (const float*)d_in[4], (const float*)d_in[5],
        (const float*)d_in[6], (const float*)d_in[7], (const float*)d_in[8],
        (const float*)d_in[9], (const float*)d_in[10], (float*)d_out);
}

// Round 2
// 1362.293 us; speedup vs baseline: 3.1225x; 3.1225x over previous
//
#include <hip/hip_runtime.h>

#define NB 4096
#define LSEQ 45
#define DMODEL 128
#define DINNER 256
#define NSTATE 4
#define RNK 8
#define USTRIDE 260   // pad vs 256: spreads row starts across banks
#define LCH 9
#define NCH 5

__device__ __forceinline__ float dot4(float4 a, float4 b) {
    return a.x*b.x + a.y*b.y + a.z*b.z + a.w*b.w;
}

__global__ __launch_bounds__(256, 2)
void mamba_fused_kernel(const float* __restrict__ x,        // B,L,DM
                        const int*   __restrict__ pad_mask, // B,L
                        const float* __restrict__ W_in,     // 2*DI, DM
                        const float* __restrict__ conv_w,   // DI,2
                        const float* __restrict__ conv_b,   // DI
                        const float* __restrict__ W_x,      // 16, DI
                        const float* __restrict__ W_dt,     // DI, RNK
                        const float* __restrict__ b_dt,     // DI
                        const float* __restrict__ A_log,    // DI, NSTATE
                        const float* __restrict__ Dvec,     // DI
                        const float* __restrict__ W_out,    // DM, DI
                        float* __restrict__ out)            // [NB*DM rep][NB*L*DM feat]
{
    const int b = blockIdx.x;
    const int t = threadIdx.x;

    __shared__ __align__(16) float s_x[LSEQ*DMODEL];     // 22.5 KB
    __shared__ __align__(16) float s_u[LSEQ*USTRIDE];    // 46.8 KB (u, then y in place)
    __shared__ __align__(16) float s_xdbl[LSEQ*16];      // 2.9 KB
    __shared__ float s_red[256];
    __shared__ float s_coff[LSEQ];
    __shared__ float s_csum;

    // ---- phase 1: stage x[b] ----
    const float* xb = x + (size_t)b*LSEQ*DMODEL;
    for (int i = t; i < LSEQ*DMODEL/4; i += 256)
        ((float4*)s_x)[i] = ((const float4*)xb)[i];
    if (t < LSEQ) s_coff[t] = 1.0f - (float)pad_mask[b*LSEQ + t];
    __syncthreads();
    if (t == 0) {
        float cs = 0.f;
        for (int l = 0; l < LSEQ; ++l) cs += s_coff[l];
        s_csum = cs;      // consumed only after later barriers
    }

    // ---- phase 2+3: xc/z projection (chunked, z stays in regs), conv+SiLU -> s_u ----
    const float cw0 = conv_w[2*t], cw1 = conv_w[2*t+1], cbv = conv_b[t];
    float z[LSEQ];
    float prevXC = 0.f;
    const float* wxc = W_in + (size_t)t * DMODEL;
    const float* wz  = W_in + (size_t)(t + DINNER) * DMODEL;
    #pragma unroll
    for (int c = 0; c < NCH; ++c) {
        float aXC[LCH], aZ[LCH];
        #pragma unroll
        for (int i = 0; i < LCH; ++i) { aXC[i] = 0.f; aZ[i] = 0.f; }
        for (int kc = 0; kc < DMODEL; kc += 8) {
            const float4 wa0 = *(const float4*)(wxc + kc);
            const float4 wa1 = *(const float4*)(wxc + kc + 4);
            const float4 wb0 = *(const float4*)(wz  + kc);
            const float4 wb1 = *(const float4*)(wz  + kc + 4);
            #pragma unroll
            for (int li = 0; li < LCH; ++li) {
                const float4* xr = (const float4*)(s_x + (c*LCH + li)*DMODEL + kc);
                const float4 x0 = xr[0], x1 = xr[1];
                aXC[li] += dot4(x0,wa0) + dot4(x1,wa1);
                aZ[li]  += dot4(x0,wb0) + dot4(x1,wb1);
            }
        }
        #pragma unroll
        for (int li = 0; li < LCH; ++li) {
            const int l = c*LCH + li;
            z[l] = aZ[li];
            const float v = cbv + aXC[li]*cw1 + prevXC*cw0;
            prevXC = aXC[li];
            s_u[l*USTRIDE + t] = v / (1.f + expf(-v));   // SiLU
        }
    }
    __syncthreads();

    // ---- phase 4: x_dbl[l][r] = u[l]·W_x[r] ----
    for (int idx = t; idx < LSEQ*16; idx += 256) {
        const int l = idx >> 4, r = idx & 15;
        const float4* ur = (const float4*)(s_u + l*USTRIDE);
        const float4* wr = (const float4*)(W_x + r*DINNER);
        float acc = 0.f;
        for (int j = 0; j < DINNER/4; ++j)
            acc += dot4(ur[j], wr[j]);
        s_xdbl[idx] = acc;
    }
    __syncthreads();

    // ---- phase 5: delta + selective scan, y -> s_u in place ----
    float wdt[RNK];
    #pragma unroll
    for (int r = 0; r < RNK; ++r) wdt[r] = W_dt[t*RNK + r];
    const float bdt = b_dt[t];
    float Av[NSTATE];
    #pragma unroll
    for (int n = 0; n < NSTATE; ++n) Av[n] = -expf(A_log[t*NSTATE + n]);
    const float Dv = Dvec[t];
    float h0 = 0.f, h1 = 0.f, h2 = 0.f, h3 = 0.f;
    #pragma unroll
    for (int l = 0; l < LSEQ; ++l) {
        const float* xd = s_xdbl + l*16;
        float dtv = bdt;
        #pragma unroll
        for (int r = 0; r < RNK; ++r) dtv += xd[r]*wdt[r];
        const float delta = (dtv > 20.f) ? dtv : log1pf(expf(dtv));
        const float ue = s_u[l*USTRIDE + t];
        const float du = delta * ue;
        h0 = expf(delta*Av[0])*h0 + du*xd[8];
        h1 = expf(delta*Av[1])*h1 + du*xd[9];
        h2 = expf(delta*Av[2])*h2 + du*xd[10];
        h3 = expf(delta*Av[3])*h3 + du*xd[11];
        float y = h0*xd[12] + h1*xd[13] + h2*xd[14] + h3*xd[15] + ue*Dv;
        const float zv = z[l];
        y *= zv / (1.f + expf(-zv));
        s_u[l*USTRIDE + t] = y;     // thread t owns column t
    }
    __syncthreads();

    // ---- phase 6: feat = y @ W_out^T, fused masked mean ----
    const int d = t & 127;
    const int half = t >> 7;
    float accF[23];
    #pragma unroll
    for (int i = 0; i < 23; ++i) accF[i] = 0.f;
    const float* wor = W_out + d*DINNER;
    for (int ec = 0; ec < DINNER; ec += 16) {
        const float4 w0 = *(const float4*)(wor + ec);
        const float4 w1 = *(const float4*)(wor + ec + 4);
        const float4 w2 = *(const float4*)(wor + ec + 8);
        const float4 w3 = *(const float4*)(wor + ec + 12);
        #pragma unroll
        for (int li = 0; li < 23; ++li) {
            const int l = 2*li + half;
            if (l < LSEQ) {
                const float4* yr = (const float4*)(s_u + l*USTRIDE + ec);
                accF[li] += dot4(yr[0],w0) + dot4(yr[1],w1)
                          + dot4(yr[2],w2) + dot4(yr[3],w3);
            }
        }
    }
    float* featb = out + (size_t)NB*DMODEL + (size_t)b*LSEQ*DMODEL;
    float racc = 0.f;
    #pragma unroll
    for (int li = 0; li < 23; ++li) {
        const int l = 2*li + half;
        if (l < LSEQ) {
            featb[l*DMODEL + d] = accF[li];
            racc += s_coff[l] * accF[li];
        }
    }
    s_red[t] = racc;
    __syncthreads();
    if (t < DMODEL)
        out[(size_t)b*DMODEL + t] = (s_red[t] + s_red[t + DMODEL]) / s_csum;
}

extern "C" void kernel_launch(void* const* d_in, const int* in_sizes, int n_in,
                              void* d_out, int out_size, void* d_ws, size_t ws_size,
                              hipStream_t stream) {
    mamba_fused_kernel<<<NB, 256, 0, stream>>>(
        (const float*)d_in[0], (const int*)d_in[1], (const float*)d_in[2],
        (const float*)d_in[3], (const float*)d_in[4], (const float*)d_in[5],
        (const float*)d_in[6], (const float*)d_in[7], (const float*)d_in[8],
        (const float*)d_in[9], (const float*)d_in[10], (float*)d_out);
}

// Round 3
// 367.216 us; speedup vs baseline: 11.5839x; 3.7098x over previous
//
#include <hip/hip_runtime.h>

#define NB 4096
#define LSEQ 45
#define DM 128
#define DI 256
#define SAUG 264      // f16 elems per row: 256 + 8 pad (16B) -> b128 reads at bank floor
#define MR 48         // padded M (rows)

typedef __attribute__((ext_vector_type(8))) _Float16 f16x8;
typedef __attribute__((ext_vector_type(4))) _Float16 f16x4;
typedef __attribute__((ext_vector_type(4))) float f32x4;

// d_ws layout in f16 elements
#define WS_WP   0        // W' [256 e][256 k]  (k<128: cw1*W_in[e], k>=128: cw0*W_in[e])
#define WS_WZ   65536    // W_in z-half [256 e][128 k]
#define WS_WX   98304    // W_x  [16 r][256 k]
#define WS_WO   102400   // W_out [128 d][256 k]
#define WS_TOT  135168

__global__ void convert_weights(const float* __restrict__ W_in,
                                const float* __restrict__ conv_w,
                                const float* __restrict__ W_x,
                                const float* __restrict__ W_out,
                                _Float16* __restrict__ ws) {
    int i = blockIdx.x * 256 + threadIdx.x;
    if (i < 65536) {
        int e = i >> 8, k = i & 255;
        float w = (k < 128) ? conv_w[2*e + 1] * W_in[e*128 + k]
                            : conv_w[2*e]     * W_in[e*128 + k - 128];
        ws[i] = (_Float16)w;
    } else if (i < 98304) {
        int j = i - 65536;
        ws[i] = (_Float16)W_in[(256 + (j >> 7))*128 + (j & 127)];
    } else if (i < 102400) {
        ws[i] = (_Float16)W_x[i - 98304];
    } else if (i < WS_TOT) {
        ws[i] = (_Float16)W_out[i - 102400];
    }
}

__global__ __launch_bounds__(256, 2)
void mamba_mfma_kernel(const float* __restrict__ x,        // B,L,DM
                       const int*   __restrict__ pad_mask, // B,L
                       const float* __restrict__ conv_b,   // DI
                       const float* __restrict__ W_dt,     // DI,8
                       const float* __restrict__ b_dt,     // DI
                       const float* __restrict__ A_log,    // DI,4
                       const float* __restrict__ Dvec,     // DI
                       const _Float16* __restrict__ ws,    // converted weights
                       float* __restrict__ out)
{
    const int b = blockIdx.x;
    const int t = threadIdx.x;
    const int lane = t & 63;
    const int wv = t >> 6;
    const int ar = lane & 15;   // A-row / B-col within tile
    const int kg = lane >> 4;   // k-group (8 contiguous k)

    __shared__ __align__(16) _Float16 s_xaug[MR * SAUG]; // x[l] || x[l-1]; later silu(z)
    __shared__ __align__(16) _Float16 s_u[MR * SAUG];    // u, then y*silu(z) in place
    __shared__ __align__(16) float s_xdbl[MR * 16];
    __shared__ float s_coff[MR];
    __shared__ float s_csum;

    _Float16* s_sz = s_xaug;   // alias: z epilogue written after barrier B

    // ---- zero staging buffer (then barrier, then fill) ----
    for (int i = t; i < MR * SAUG / 8; i += 256)
        ((f32x4*)s_xaug)[i] = f32x4{0.f, 0.f, 0.f, 0.f};
    if (t < MR) s_coff[t] = (t < LSEQ) ? 1.0f - (float)pad_mask[b*LSEQ + t] : 0.f;
    __syncthreads();

    const float* xb = x + (size_t)b * LSEQ * DM;
    for (int idx = t; idx < LSEQ * 32; idx += 256) {
        const int row = idx >> 5;
        const int c4 = (idx & 31) << 2;
        const float4 v = *(const float4*)(xb + row*DM + c4);
        f16x4 h; h.x = (_Float16)v.x; h.y = (_Float16)v.y;
        h.z = (_Float16)v.z; h.w = (_Float16)v.w;
        *(f16x4*)(s_xaug + row*SAUG + c4) = h;            // x[l] at cols 0:128
        *(f16x4*)(s_xaug + (row+1)*SAUG + DM + c4) = h;   // x[l-1] at cols 128:256 of row l
    }
    __syncthreads();   // barrier A
    if (t == 0) {
        float cs = 0.f;
        for (int l = 0; l < LSEQ; ++l) cs += s_coff[l];
        s_csum = cs;
    }

    // ---- GEMM1: [48 x 256k] @ W'^T -> xc_conv [48 x 256], and z-half (K=128) ----
    f32x4 aXC[4][3], aZ[4][3];
    #pragma unroll
    for (int j = 0; j < 4; ++j)
        #pragma unroll
        for (int m = 0; m < 3; ++m) {
            aXC[j][m] = f32x4{0.f,0.f,0.f,0.f};
            aZ[j][m]  = f32x4{0.f,0.f,0.f,0.f};
        }
    const _Float16* Wp  = ws + WS_WP;
    const _Float16* Wzp = ws + WS_WZ;
    #pragma unroll
    for (int ks = 0; ks < 8; ++ks) {
        f16x8 afr[3];
        #pragma unroll
        for (int m = 0; m < 3; ++m)
            afr[m] = *(const f16x8*)(s_xaug + (m*16 + ar)*SAUG + ks*32 + kg*8);
        #pragma unroll
        for (int j = 0; j < 4; ++j) {
            const int e = (wv*4 + j)*16 + ar;
            f16x8 bfr = *(const f16x8*)(Wp + e*256 + ks*32 + kg*8);
            #pragma unroll
            for (int m = 0; m < 3; ++m)
                aXC[j][m] = __builtin_amdgcn_mfma_f32_16x16x32_f16(afr[m], bfr, aXC[j][m], 0, 0, 0);
        }
        if (ks < 4) {
            #pragma unroll
            for (int j = 0; j < 4; ++j) {
                const int e = (wv*4 + j)*16 + ar;
                f16x8 bfr = *(const f16x8*)(Wzp + e*128 + ks*32 + kg*8);
                #pragma unroll
                for (int m = 0; m < 3; ++m)
                    aZ[j][m] = __builtin_amdgcn_mfma_f32_16x16x32_f16(afr[m], bfr, aZ[j][m], 0, 0, 0);
            }
        }
    }

    // ---- epilogue xc: + conv_b, SiLU -> s_u (f16) ----
    #pragma unroll
    for (int j = 0; j < 4; ++j) {
        const int e = (wv*4 + j)*16 + ar;   // C col = lane&15
        const float cbe = conv_b[e];
        #pragma unroll
        for (int m = 0; m < 3; ++m)
            #pragma unroll
            for (int i = 0; i < 4; ++i) {
                const int row = m*16 + kg*4 + i;
                const float v = aXC[j][m][i] + cbe;
                s_u[row*SAUG + e] = (_Float16)(v / (1.f + __expf(-v)));
            }
    }
    __syncthreads();   // barrier B: s_xaug dead, s_u complete

    // ---- epilogue z: silu(z) -> s_sz (aliases s_xaug) ----
    #pragma unroll
    for (int j = 0; j < 4; ++j) {
        const int e = (wv*4 + j)*16 + ar;
        #pragma unroll
        for (int m = 0; m < 3; ++m)
            #pragma unroll
            for (int i = 0; i < 4; ++i) {
                const int row = m*16 + kg*4 + i;
                const float zv = aZ[j][m][i];
                s_sz[row*SAUG + e] = (_Float16)(zv / (1.f + __expf(-zv)));
            }
    }

    // ---- GEMM2: x_dbl = u @ W_x^T  [48 x 16], m-tile per wave (waves 0-2) ----
    if (wv < 3) {
        f32x4 acc = f32x4{0.f,0.f,0.f,0.f};
        const _Float16* Wxp = ws + WS_WX;
        #pragma unroll
        for (int ks = 0; ks < 8; ++ks) {
            f16x8 afr = *(const f16x8*)(s_u + (wv*16 + ar)*SAUG + ks*32 + kg*8);
            f16x8 bfr = *(const f16x8*)(Wxp + ar*256 + ks*32 + kg*8);
            acc = __builtin_amdgcn_mfma_f32_16x16x32_f16(afr, bfr, acc, 0, 0, 0);
        }
        #pragma unroll
        for (int i = 0; i < 4; ++i)
            s_xdbl[(wv*16 + kg*4 + i)*16 + ar] = acc[i];
    }
    __syncthreads();   // barrier C: s_xdbl + s_sz ready

    // ---- scan: channel t, sequential over l (fp32) ----
    {
        const int e = t;
        float wdt[8];
        #pragma unroll
        for (int r = 0; r < 8; ++r) wdt[r] = W_dt[e*8 + r];
        const float bdt = b_dt[e];
        float Av[4];
        #pragma unroll
        for (int n = 0; n < 4; ++n) Av[n] = -__expf(A_log[e*4 + n]);
        const float Dv = Dvec[e];
        float h0 = 0.f, h1 = 0.f, h2 = 0.f, h3 = 0.f;
        for (int l = 0; l < LSEQ; ++l) {
            const float* xd = s_xdbl + l*16;
            float dtv = bdt;
            #pragma unroll
            for (int r = 0; r < 8; ++r) dtv += xd[r]*wdt[r];
            const float delta = (dtv > 20.f) ? dtv : log1pf(__expf(dtv));
            const float ue = (float)s_u[l*SAUG + e];
            const float du = delta * ue;
            h0 = __expf(delta*Av[0])*h0 + du*xd[8];
            h1 = __expf(delta*Av[1])*h1 + du*xd[9];
            h2 = __expf(delta*Av[2])*h2 + du*xd[10];
            h3 = __expf(delta*Av[3])*h3 + du*xd[11];
            float y = h0*xd[12] + h1*xd[13] + h2*xd[14] + h3*xd[15] + ue*Dv;
            y *= (float)s_sz[l*SAUG + e];
            s_u[l*SAUG + e] = (_Float16)y;   // in place, column-owned
        }
    }
    __syncthreads();   // barrier D: y ready

    // ---- GEMM3: feat = y @ W_out^T [48 x 128], fused masked mean ----
    {
        f32x4 acc[2][3];
        #pragma unroll
        for (int jn = 0; jn < 2; ++jn)
            #pragma unroll
            for (int m = 0; m < 3; ++m) acc[jn][m] = f32x4{0.f,0.f,0.f,0.f};
        const _Float16* Wop = ws + WS_WO;
        #pragma unroll
        for (int ks = 0; ks < 8; ++ks) {
            f16x8 afr[3];
            #pragma unroll
            for (int m = 0; m < 3; ++m)
                afr[m] = *(const f16x8*)(s_u + (m*16 + ar)*SAUG + ks*32 + kg*8);
            #pragma unroll
            for (int jn = 0; jn < 2; ++jn) {
                const int d0 = (wv*2 + jn)*16 + ar;
                f16x8 bfr = *(const f16x8*)(Wop + d0*256 + ks*32 + kg*8);
                #pragma unroll
                for (int m = 0; m < 3; ++m)
                    acc[jn][m] = __builtin_amdgcn_mfma_f32_16x16x32_f16(afr[m], bfr, acc[jn][m], 0, 0, 0);
            }
        }
        float* featb = out + (size_t)NB*DM + (size_t)b*LSEQ*DM;
        float arep[2] = {0.f, 0.f};
        #pragma unroll
        for (int m = 0; m < 3; ++m)
            #pragma unroll
            for (int i = 0; i < 4; ++i) {
                const int row = m*16 + kg*4 + i;
                if (row < LSEQ) {
                    const float cf = s_coff[row];
                    #pragma unroll
                    for (int jn = 0; jn < 2; ++jn) {
                        const int col = (wv*2 + jn)*16 + ar;
                        const float v = acc[jn][m][i];
                        featb[row*DM + col] = v;
                        arep[jn] += cf * v;
                    }
                }
            }
        #pragma unroll
        for (int jn = 0; jn < 2; ++jn) {
            float r = arep[jn];
            r += __shfl_xor(r, 16);
            r += __shfl_xor(r, 32);
            if (kg == 0)
                out[(size_t)b*DM + (wv*2 + jn)*16 + ar] = r / s_csum;
        }
    }
}

extern "C" void kernel_launch(void* const* d_in, const int* in_sizes, int n_in,
                              void* d_out, int out_size, void* d_ws, size_t ws_size,
                              hipStream_t stream) {
    const float* x        = (const float*)d_in[0];
    const int*   pad_mask = (const int*)d_in[1];
    const float* W_in     = (const float*)d_in[2];
    const float* conv_w   = (const float*)d_in[3];
    const float* conv_b   = (const float*)d_in[4];
    const float* W_x      = (const float*)d_in[5];
    const float* W_dt     = (const float*)d_in[6];
    const float* b_dt     = (const float*)d_in[7];
    const float* A_log    = (const float*)d_in[8];
    const float* Dvec     = (const float*)d_in[9];
    const float* W_out    = (const float*)d_in[10];
    _Float16* ws = (_Float16*)d_ws;

    convert_weights<<<(WS_TOT + 255)/256, 256, 0, stream>>>(W_in, conv_w, W_x, W_out, ws);
    mamba_mfma_kernel<<<NB, 256, 0, stream>>>(x, pad_mask, conv_b, W_dt, b_dt,
                                              A_log, Dvec, ws, (float*)d_out);
}

// Round 4
// 245.758 us; speedup vs baseline: 17.3088x; 1.4942x over previous
//
#include <hip/hip_runtime.h>

#define NB 4096
#define LSEQ 45
#define DM 128
#define DI 256
#define SAUG 264   // s_u row stride (f16): 256 + 8 pad
#define SZS  260   // s_sz row stride (f16)
#define SX   136   // s_x row stride (f16): 128 + 8 pad
#define MR 48

typedef __attribute__((ext_vector_type(8))) _Float16 f16x8;
typedef __attribute__((ext_vector_type(4))) _Float16 f16x4;
typedef __attribute__((ext_vector_type(4))) float f32x4;

// d_ws layout in f16 elements
#define WS_WP   0        // W' [256 e][256 k]  (k<128: cw1*W_in[e], k>=128: cw0*W_in[e])
#define WS_WZ   65536    // W_in z-half [256 e][128 k]
#define WS_WX   98304    // W_x  [16 r][256 k]
#define WS_WO   102400   // W_out [128 d][256 k]
#define WS_TOT  135168

__global__ void convert_weights(const float* __restrict__ W_in,
                                const float* __restrict__ conv_w,
                                const float* __restrict__ W_x,
                                const float* __restrict__ W_out,
                                _Float16* __restrict__ ws) {
    int i = blockIdx.x * 256 + threadIdx.x;
    if (i < 65536) {
        int e = i >> 8, k = i & 255;
        float w = (k < 128) ? conv_w[2*e + 1] * W_in[e*128 + k]
                            : conv_w[2*e]     * W_in[e*128 + k - 128];
        ws[i] = (_Float16)w;
    } else if (i < 98304) {
        int j = i - 65536;
        ws[i] = (_Float16)W_in[(256 + (j >> 7))*128 + (j & 127)];
    } else if (i < 102400) {
        ws[i] = (_Float16)W_x[i - 98304];
    } else if (i < WS_TOT) {
        ws[i] = (_Float16)W_out[i - 102400];
    }
}

__device__ __forceinline__ float fast_silu(float v) {
    return v * __builtin_amdgcn_rcpf(1.f + __expf(-v));
}

__global__ __launch_bounds__(256, 2)
void mamba_mfma_kernel(const float* __restrict__ x,        // B,L,DM
                       const int*   __restrict__ pad_mask, // B,L
                       const float* __restrict__ conv_b,   // DI
                       const float* __restrict__ W_dt,     // DI,8
                       const float* __restrict__ b_dt,     // DI
                       const float* __restrict__ A_log,    // DI,4
                       const float* __restrict__ Dvec,     // DI
                       const _Float16* __restrict__ ws,    // converted weights
                       float* __restrict__ out)
{
    const int b = blockIdx.x;
    const int t = threadIdx.x;
    const int lane = t & 63;
    const int wv = t >> 6;
    const int ar = lane & 15;   // A-row / B-col within tile
    const int kg = lane >> 4;   // k-group (8 contiguous k)

    // ---- manually-carved LDS pool (53.6 KB -> 3 blocks/CU) ----
    __shared__ __align__(16) unsigned char pool[53600];
    _Float16* s_u    = (_Float16*)pool;                    // 48*264*2 = 25344
    _Float16* s_x    = (_Float16*)(pool + 25344);          // 49*136*2 = 13328 (dead after GEMM1)
    _Float16* s_sz   = (_Float16*)(pool + 25344);          // 48*260*2 = 24960 (aliases s_x)
    float*    s_xdbl = (float*)(pool + 50304);             // 48*16*4  = 3072
    float*    s_coff = (float*)(pool + 53376);             // 48*4
    float*    s_inv  = (float*)(pool + 53568);             // 4

    // ---- stage x[b] into shifted s_x: row 0 = zeros, row l+1 = x[l]; rows 46-48 zero ----
    for (int i = t; i < 4*17; i += 256) {                  // zero rows {0,46,47,48}
        const int rr = i / 17, c = i % 17;
        const int row = (rr == 0) ? 0 : 45 + rr;
        ((f32x4*)(s_x + row*SX))[c] = f32x4{0.f,0.f,0.f,0.f};
    }
    const float* xb = x + (size_t)b * LSEQ * DM;
    for (int idx = t; idx < LSEQ * 32; idx += 256) {
        const int row = idx >> 5;
        const int c4 = (idx & 31) << 2;
        const float4 v = *(const float4*)(xb + row*DM + c4);
        f16x4 h; h.x = (_Float16)v.x; h.y = (_Float16)v.y;
        h.z = (_Float16)v.z; h.w = (_Float16)v.w;
        *(f16x4*)(s_x + (row+1)*SX + c4) = h;
    }
    if (t < MR) s_coff[t] = (t < LSEQ) ? 1.0f - (float)pad_mask[b*LSEQ + t] : 0.f;
    __syncthreads();   // barrier A
    if (t == 0) {
        float cs = 0.f;
        for (int l = 0; l < LSEQ; ++l) cs += s_coff[l];
        s_inv[0] = __builtin_amdgcn_rcpf(cs);
    }

    // ---- GEMM1: xc_conv = [x[l] | x[l-1]] @ W'^T (K=256), z = x[l] @ Wz^T (K=128) ----
    f32x4 aXC[4][3], aZ[4][3];
    #pragma unroll
    for (int j = 0; j < 4; ++j)
        #pragma unroll
        for (int m = 0; m < 3; ++m) {
            aXC[j][m] = f32x4{0.f,0.f,0.f,0.f};
            aZ[j][m]  = f32x4{0.f,0.f,0.f,0.f};
        }
    const _Float16* Wp  = ws + WS_WP;
    const _Float16* Wzp = ws + WS_WZ;
    #pragma unroll
    for (int ks = 0; ks < 8; ++ks) {
        f16x8 afr[3];
        #pragma unroll
        for (int m = 0; m < 3; ++m) {
            const int row = m*16 + ar;
            afr[m] = (ks < 4)
                ? *(const f16x8*)(s_x + (row+1)*SX + ks*32 + kg*8)        // x[l] half
                : *(const f16x8*)(s_x + row*SX + (ks-4)*32 + kg*8);       // x[l-1] half
        }
        #pragma unroll
        for (int j = 0; j < 4; ++j) {
            const int e = (wv*4 + j)*16 + ar;
            f16x8 bfr = *(const f16x8*)(Wp + e*256 + ks*32 + kg*8);
            #pragma unroll
            for (int m = 0; m < 3; ++m)
                aXC[j][m] = __builtin_amdgcn_mfma_f32_16x16x32_f16(afr[m], bfr, aXC[j][m], 0, 0, 0);
        }
        if (ks < 4) {
            #pragma unroll
            for (int j = 0; j < 4; ++j) {
                const int e = (wv*4 + j)*16 + ar;
                f16x8 bfr = *(const f16x8*)(Wzp + e*128 + ks*32 + kg*8);
                #pragma unroll
                for (int m = 0; m < 3; ++m)
                    aZ[j][m] = __builtin_amdgcn_mfma_f32_16x16x32_f16(afr[m], bfr, aZ[j][m], 0, 0, 0);
            }
        }
    }

    // ---- epilogue xc: + conv_b, SiLU -> s_u (f16) ----
    #pragma unroll
    for (int j = 0; j < 4; ++j) {
        const int e = (wv*4 + j)*16 + ar;   // C col = lane&15
        const float cbe = conv_b[e];
        #pragma unroll
        for (int m = 0; m < 3; ++m)
            #pragma unroll
            for (int i = 0; i < 4; ++i) {
                const int row = m*16 + kg*4 + i;
                s_u[row*SAUG + e] = (_Float16)fast_silu(aXC[j][m][i] + cbe);
            }
    }
    __syncthreads();   // barrier B: s_x dead, s_u complete

    // ---- epilogue z: silu(z) -> s_sz (aliases s_x region) ----
    #pragma unroll
    for (int j = 0; j < 4; ++j) {
        const int e = (wv*4 + j)*16 + ar;
        #pragma unroll
        for (int m = 0; m < 3; ++m)
            #pragma unroll
            for (int i = 0; i < 4; ++i) {
                const int row = m*16 + kg*4 + i;
                s_sz[row*SZS + e] = (_Float16)fast_silu(aZ[j][m][i]);
            }
    }

    // ---- GEMM2: x_dbl = u @ W_x^T  [48 x 16], m-tile per wave (waves 0-2) ----
    if (wv < 3) {
        f32x4 acc = f32x4{0.f,0.f,0.f,0.f};
        const _Float16* Wxp = ws + WS_WX;
        #pragma unroll
        for (int ks = 0; ks < 8; ++ks) {
            f16x8 afr = *(const f16x8*)(s_u + (wv*16 + ar)*SAUG + ks*32 + kg*8);
            f16x8 bfr = *(const f16x8*)(Wxp + ar*256 + ks*32 + kg*8);
            acc = __builtin_amdgcn_mfma_f32_16x16x32_f16(afr, bfr, acc, 0, 0, 0);
        }
        #pragma unroll
        for (int i = 0; i < 4; ++i)
            s_xdbl[(wv*16 + kg*4 + i)*16 + ar] = acc[i];
    }
    __syncthreads();   // barrier C: s_xdbl + s_sz ready

    // ---- scan: channel t, sequential over l (fp32) ----
    {
        const int e = t;
        const float4 wdtA = *(const float4*)(W_dt + e*8);
        const float4 wdtB = *(const float4*)(W_dt + e*8 + 4);
        const float bdt = b_dt[e];
        float Av[4];
        #pragma unroll
        for (int n = 0; n < 4; ++n) Av[n] = -__expf(A_log[e*4 + n]);
        const float Dv = Dvec[e];
        float h0 = 0.f, h1 = 0.f, h2 = 0.f, h3 = 0.f;
        #pragma unroll 5
        for (int l = 0; l < LSEQ; ++l) {
            const float4* xd = (const float4*)(s_xdbl + l*16);
            const float4 xd0 = xd[0], xd1 = xd[1], xdB = xd[2], xdC = xd[3];
            float dtv = bdt;
            dtv += xd0.x*wdtA.x + xd0.y*wdtA.y + xd0.z*wdtA.z + xd0.w*wdtA.w;
            dtv += xd1.x*wdtB.x + xd1.y*wdtB.y + xd1.z*wdtB.z + xd1.w*wdtB.w;
            // stable native softplus
            const float delta = fmaxf(dtv, 0.f) + __logf(1.f + __expf(-fabsf(dtv)));
            const float ue = (float)s_u[l*SAUG + e];
            const float du = delta * ue;
            h0 = __expf(delta*Av[0])*h0 + du*xdB.x;
            h1 = __expf(delta*Av[1])*h1 + du*xdB.y;
            h2 = __expf(delta*Av[2])*h2 + du*xdB.z;
            h3 = __expf(delta*Av[3])*h3 + du*xdB.w;
            float y = h0*xdC.x + h1*xdC.y + h2*xdC.z + h3*xdC.w + ue*Dv;
            y *= (float)s_sz[l*SZS + e];
            s_u[l*SAUG + e] = (_Float16)y;   // in place, column-owned
        }
    }
    __syncthreads();   // barrier D: y ready

    // ---- GEMM3: feat = y @ W_out^T [48 x 128], fused masked mean ----
    {
        f32x4 acc[2][3];
        #pragma unroll
        for (int jn = 0; jn < 2; ++jn)
            #pragma unroll
            for (int m = 0; m < 3; ++m) acc[jn][m] = f32x4{0.f,0.f,0.f,0.f};
        const _Float16* Wop = ws + WS_WO;
        #pragma unroll
        for (int ks = 0; ks < 8; ++ks) {
            f16x8 afr[3];
            #pragma unroll
            for (int m = 0; m < 3; ++m)
                afr[m] = *(const f16x8*)(s_u + (m*16 + ar)*SAUG + ks*32 + kg*8);
            #pragma unroll
            for (int jn = 0; jn < 2; ++jn) {
                const int d0 = (wv*2 + jn)*16 + ar;
                f16x8 bfr = *(const f16x8*)(Wop + d0*256 + ks*32 + kg*8);
                #pragma unroll
                for (int m = 0; m < 3; ++m)
                    acc[jn][m] = __builtin_amdgcn_mfma_f32_16x16x32_f16(afr[m], bfr, acc[jn][m], 0, 0, 0);
            }
        }
        float* featb = out + (size_t)NB*DM + (size_t)b*LSEQ*DM;
        float arep[2] = {0.f, 0.f};
        #pragma unroll
        for (int m = 0; m < 3; ++m)
            #pragma unroll
            for (int i = 0; i < 4; ++i) {
                const int row = m*16 + kg*4 + i;
                if (row < LSEQ) {
                    const float cf = s_coff[row];
                    #pragma unroll
                    for (int jn = 0; jn < 2; ++jn) {
                        const int col = (wv*2 + jn)*16 + ar;
                        const float v = acc[jn][m][i];
                        featb[row*DM + col] = v;
                        arep[jn] += cf * v;
                    }
                }
            }
        const float inv = s_inv[0];
        #pragma unroll
        for (int jn = 0; jn < 2; ++jn) {
            float r = arep[jn];
            r += __shfl_xor(r, 16);
            r += __shfl_xor(r, 32);
            if (kg == 0)
                out[(size_t)b*DM + (wv*2 + jn)*16 + ar] = r * inv;
        }
    }
}

extern "C" void kernel_launch(void* const* d_in, const int* in_sizes, int n_in,
                              void* d_out, int out_size, void* d_ws, size_t ws_size,
                              hipStream_t stream) {
    const float* x        = (const float*)d_in[0];
    const int*   pad_mask = (const int*)d_in[1];
    const float* W_in     = (const float*)d_in[2];
    const float* conv_w   = (const float*)d_in[3];
    const float* conv_b   = (const float*)d_in[4];
    const float* W_x      = (const float*)d_in[5];
    const float* W_dt     = (const float*)d_in[6];
    const float* b_dt     = (const float*)d_in[7];
    const float* A_log    = (const float*)d_in[8];
    const float* Dvec     = (const float*)d_in[9];
    const float* W_out    = (const float*)d_in[10];
    _Float16* ws = (_Float16*)d_ws;

    convert_weights<<<(WS_TOT + 255)/256, 256, 0, stream>>>(W_in, conv_w, W_x, W_out, ws);
    mamba_mfma_kernel<<<NB, 256, 0, stream>>>(x, pad_mask, conv_b, W_dt, b_dt,
                                              A_log, Dvec, ws, (float*)d_out);
}

// Round 5
// 187.112 us; speedup vs baseline: 22.7338x; 1.3134x over previous
//
#include <hip/hip_runtime.h>

#define NB 4096
#define LSEQ 45
#define DM 128
#define DI 256
#define SAUG 264   // s_u row stride (f16): 256 + 8 pad (16B)
#define SX   136   // s_x row stride (f16): 128 + 8 pad (16B); pad hosts coff/inv
#define MR 48

typedef __attribute__((ext_vector_type(8))) _Float16 f16x8;
typedef __attribute__((ext_vector_type(4))) _Float16 f16x4;
typedef __attribute__((ext_vector_type(4))) float f32x4;

// d_ws layout in f16 elements
#define WS_WP   0        // W' [256 e][256 k]  (k<128: cw1*W_in[e], k>=128: cw0*W_in[e])
#define WS_WZ   65536    // W_in z-half [256 e][128 k]
#define WS_WX   98304    // W_x  [16 r][256 k]
#define WS_WO   102400   // W_out [128 d][256 k]
#define WS_TOT  135168

__global__ void convert_weights(const float* __restrict__ W_in,
                                const float* __restrict__ conv_w,
                                const float* __restrict__ W_x,
                                const float* __restrict__ W_out,
                                _Float16* __restrict__ ws) {
    int i = blockIdx.x * 256 + threadIdx.x;
    if (i < 65536) {
        int e = i >> 8, k = i & 255;
        float w = (k < 128) ? conv_w[2*e + 1] * W_in[e*128 + k]
                            : conv_w[2*e]     * W_in[e*128 + k - 128];
        ws[i] = (_Float16)w;
    } else if (i < 98304) {
        int j = i - 65536;
        ws[i] = (_Float16)W_in[(256 + (j >> 7))*128 + (j & 127)];
    } else if (i < 102400) {
        ws[i] = (_Float16)W_x[i - 98304];
    } else if (i < WS_TOT) {
        ws[i] = (_Float16)W_out[i - 102400];
    }
}

__device__ __forceinline__ float fast_silu(float v) {
    return v * __builtin_amdgcn_rcpf(1.f + __expf(-v));
}

__global__ __launch_bounds__(256, 4)
void mamba_mfma_kernel(const float* __restrict__ x,        // B,L,DM
                       const int*   __restrict__ pad_mask, // B,L
                       const float* __restrict__ conv_b,   // DI
                       const float* __restrict__ W_dt,     // DI,8
                       const float* __restrict__ b_dt,     // DI
                       const float* __restrict__ A_log,    // DI,4
                       const float* __restrict__ Dvec,     // DI
                       const _Float16* __restrict__ ws,    // converted weights
                       float* __restrict__ out)
{
    const int b = blockIdx.x;
    const int t = threadIdx.x;
    const int lane = t & 63;
    const int wv = t >> 6;
    const int ar = lane & 15;   // A-row / B-col within tile
    const int kg = lane >> 4;   // k-group (8 contiguous k)

    // ---- carved LDS pool: 40880 B -> rounds to 40960 -> exactly 4 blocks/CU ----
    __shared__ __align__(16) unsigned char pool[40880];
    _Float16* s_u  = (_Float16*)pool;                 // 48*264*2 = 25344
    _Float16* s_x  = (_Float16*)(pool + 25344);       // 49*136*2 = 13328 (shifted: row l+1 = x[l])
    _Float16* s_dt = (_Float16*)(pool + 38672);       // 48*8*2   = 768   (x_dbl dt cols, f16)
    float*    s_bc = (float*)(pool + 39440);          // 45*8*4   = 1440  (x_dbl B,C cols, f32)
    // coff[l] lives at s_x row (l+1) pad: *(float*)(s_x + (l+1)*SX + 128)
    // 1/csum lives at s_x row 0 pad:     *(float*)(s_x + 128)

    // ---- stage: zero rows {0,46,47,48}; x[l] -> s_x row l+1; coff -> pads ----
    for (int i = t; i < 4*17; i += 256) {
        const int rr = i / 17, c = i % 17;
        const int row = (rr == 0) ? 0 : 45 + rr;
        ((f32x4*)(s_x + row*SX))[c] = f32x4{0.f,0.f,0.f,0.f};
    }
    const float* xb = x + (size_t)b * LSEQ * DM;
    for (int idx = t; idx < LSEQ * 32; idx += 256) {
        const int row = idx >> 5;
        const int c4 = (idx & 31) << 2;
        const float4 v = *(const float4*)(xb + row*DM + c4);
        f16x4 h; h.x = (_Float16)v.x; h.y = (_Float16)v.y;
        h.z = (_Float16)v.z; h.w = (_Float16)v.w;
        *(f16x4*)(s_x + (row+1)*SX + c4) = h;
    }
    if (t < LSEQ)
        *(float*)(s_x + (t+1)*SX + 128) = 1.0f - (float)pad_mask[b*LSEQ + t];
    __syncthreads();   // barrier A
    if (t == 0) {
        float cs = 0.f;
        for (int l = 0; l < LSEQ; ++l) cs += *(const float*)(s_x + (l+1)*SX + 128);
        *(float*)(s_x + 128) = __builtin_amdgcn_rcpf(cs);
    }

    // ---- pass 1: xc_conv = [x[l] | x[l-1]] @ W'^T (K=256) -> silu -> s_u ----
    {
        f32x4 acc[4][3];
        #pragma unroll
        for (int j = 0; j < 4; ++j)
            #pragma unroll
            for (int m = 0; m < 3; ++m) acc[j][m] = f32x4{0.f,0.f,0.f,0.f};
        const _Float16* Wp = ws + WS_WP;
        #pragma unroll
        for (int ks = 0; ks < 8; ++ks) {
            f16x8 afr[3];
            #pragma unroll
            for (int m = 0; m < 3; ++m) {
                const int row = m*16 + ar;
                afr[m] = (ks < 4)
                    ? *(const f16x8*)(s_x + (row+1)*SX + ks*32 + kg*8)
                    : *(const f16x8*)(s_x + row*SX + (ks-4)*32 + kg*8);
            }
            #pragma unroll
            for (int j = 0; j < 4; ++j) {
                const int e = (wv*4 + j)*16 + ar;
                f16x8 bfr = *(const f16x8*)(Wp + e*256 + ks*32 + kg*8);
                #pragma unroll
                for (int m = 0; m < 3; ++m)
                    acc[j][m] = __builtin_amdgcn_mfma_f32_16x16x32_f16(afr[m], bfr, acc[j][m], 0, 0, 0);
            }
        }
        #pragma unroll
        for (int j = 0; j < 4; ++j) {
            const int e = (wv*4 + j)*16 + ar;
            const float cbe = conv_b[e];
            #pragma unroll
            for (int m = 0; m < 3; ++m)
                #pragma unroll
                for (int i = 0; i < 4; ++i) {
                    const int row = m*16 + kg*4 + i;
                    s_u[row*SAUG + e] = (_Float16)fast_silu(acc[j][m][i] + cbe);
                }
        }
    }
    __syncthreads();   // barrier B: s_u ready

    // ---- GEMM2: x_dbl = u @ W_x^T [48 x 16] on waves 0-2; dt->f16, B/C->f32 ----
    if (wv < 3) {
        f32x4 acc = f32x4{0.f,0.f,0.f,0.f};
        const _Float16* Wxp = ws + WS_WX;
        #pragma unroll
        for (int ks = 0; ks < 8; ++ks) {
            f16x8 afr = *(const f16x8*)(s_u + (wv*16 + ar)*SAUG + ks*32 + kg*8);
            f16x8 bfr = *(const f16x8*)(Wxp + ar*256 + ks*32 + kg*8);
            acc = __builtin_amdgcn_mfma_f32_16x16x32_f16(afr, bfr, acc, 0, 0, 0);
        }
        #pragma unroll
        for (int i = 0; i < 4; ++i) {
            const int row = wv*16 + kg*4 + i;
            if (ar < 8) s_dt[row*8 + ar] = (_Float16)acc[i];
            else if (row < LSEQ) s_bc[row*8 + (ar - 8)] = acc[i];
        }
    }
    __syncthreads();   // barrier C

    // ---- scan: channel t over l; y_pre = scan + u*D -> s_u in place ----
    {
        const int e = t;
        const float4 wdtA = *(const float4*)(W_dt + e*8);
        const float4 wdtB = *(const float4*)(W_dt + e*8 + 4);
        const float bdt = b_dt[e];
        float Av[4];
        #pragma unroll
        for (int n = 0; n < 4; ++n) Av[n] = -__expf(A_log[e*4 + n]);
        const float Dv = Dvec[e];
        float h0 = 0.f, h1 = 0.f, h2 = 0.f, h3 = 0.f;
        for (int l = 0; l < LSEQ; ++l) {
            const f16x8 dt8 = *(const f16x8*)(s_dt + l*8);   // broadcast
            float dtv = bdt;
            dtv += (float)dt8[0]*wdtA.x + (float)dt8[1]*wdtA.y
                 + (float)dt8[2]*wdtA.z + (float)dt8[3]*wdtA.w;
            dtv += (float)dt8[4]*wdtB.x + (float)dt8[5]*wdtB.y
                 + (float)dt8[6]*wdtB.z + (float)dt8[7]*wdtB.w;
            const float delta = fmaxf(dtv, 0.f) + __logf(1.f + __expf(-fabsf(dtv)));
            const f32x4 xB = *(const f32x4*)(s_bc + l*8);     // broadcast
            const f32x4 xC = *(const f32x4*)(s_bc + l*8 + 4); // broadcast
            const float ue = (float)s_u[l*SAUG + e];
            const float du = delta * ue;
            h0 = __expf(delta*Av[0])*h0 + du*xB[0];
            h1 = __expf(delta*Av[1])*h1 + du*xB[1];
            h2 = __expf(delta*Av[2])*h2 + du*xB[2];
            h3 = __expf(delta*Av[3])*h3 + du*xB[3];
            const float y = h0*xC[0] + h1*xC[1] + h2*xC[2] + h3*xC[3] + ue*Dv;
            s_u[l*SAUG + e] = (_Float16)y;   // column-owned
        }
    }
    __syncthreads();   // barrier D: y_pre ready

    // ---- pass 2: z = x @ Wz^T (K=128); y = y_pre * silu(z) in place ----
    {
        f32x4 acc[4][3];
        #pragma unroll
        for (int j = 0; j < 4; ++j)
            #pragma unroll
            for (int m = 0; m < 3; ++m) acc[j][m] = f32x4{0.f,0.f,0.f,0.f};
        const _Float16* Wzp = ws + WS_WZ;
        #pragma unroll
        for (int ks = 0; ks < 4; ++ks) {
            f16x8 afr[3];
            #pragma unroll
            for (int m = 0; m < 3; ++m)
                afr[m] = *(const f16x8*)(s_x + (m*16 + ar + 1)*SX + ks*32 + kg*8);
            #pragma unroll
            for (int j = 0; j < 4; ++j) {
                const int e = (wv*4 + j)*16 + ar;
                f16x8 bfr = *(const f16x8*)(Wzp + e*128 + ks*32 + kg*8);
                #pragma unroll
                for (int m = 0; m < 3; ++m)
                    acc[j][m] = __builtin_amdgcn_mfma_f32_16x16x32_f16(afr[m], bfr, acc[j][m], 0, 0, 0);
            }
        }
        #pragma unroll
        for (int j = 0; j < 4; ++j) {
            const int e = (wv*4 + j)*16 + ar;
            #pragma unroll
            for (int m = 0; m < 3; ++m)
                #pragma unroll
                for (int i = 0; i < 4; ++i) {
                    const int row = m*16 + kg*4 + i;
                    const float yv = (float)s_u[row*SAUG + e];
                    s_u[row*SAUG + e] = (_Float16)(yv * fast_silu(acc[j][m][i]));
                }
        }
    }
    __syncthreads();   // barrier E: y ready

    // ---- GEMM3: feat = y @ W_out^T [48 x 128], fused masked mean ----
    {
        f32x4 acc[2][3];
        #pragma unroll
        for (int jn = 0; jn < 2; ++jn)
            #pragma unroll
            for (int m = 0; m < 3; ++m) acc[jn][m] = f32x4{0.f,0.f,0.f,0.f};
        const _Float16* Wop = ws + WS_WO;
        #pragma unroll
        for (int ks = 0; ks < 8; ++ks) {
            f16x8 afr[3];
            #pragma unroll
            for (int m = 0; m < 3; ++m)
                afr[m] = *(const f16x8*)(s_u + (m*16 + ar)*SAUG + ks*32 + kg*8);
            #pragma unroll
            for (int jn = 0; jn < 2; ++jn) {
                const int d0 = (wv*2 + jn)*16 + ar;
                f16x8 bfr = *(const f16x8*)(Wop + d0*256 + ks*32 + kg*8);
                #pragma unroll
                for (int m = 0; m < 3; ++m)
                    acc[jn][m] = __builtin_amdgcn_mfma_f32_16x16x32_f16(afr[m], bfr, acc[jn][m], 0, 0, 0);
            }
        }
        float* featb = out + (size_t)NB*DM + (size_t)b*LSEQ*DM;
        float arep[2] = {0.f, 0.f};
        #pragma unroll
        for (int m = 0; m < 3; ++m)
            #pragma unroll
            for (int i = 0; i < 4; ++i) {
                const int row = m*16 + kg*4 + i;
                if (row < LSEQ) {
                    const float cf = *(const float*)(s_x + (row+1)*SX + 128);
                    #pragma unroll
                    for (int jn = 0; jn < 2; ++jn) {
                        const int col = (wv*2 + jn)*16 + ar;
                        const float v = acc[jn][m][i];
                        featb[row*DM + col] = v;
                        arep[jn] += cf * v;
                    }
                }
            }
        const float inv = *(const float*)(s_x + 128);
        #pragma unroll
        for (int jn = 0; jn < 2; ++jn) {
            float r = arep[jn];
            r += __shfl_xor(r, 16);
            r += __shfl_xor(r, 32);
            if (kg == 0)
                out[(size_t)b*DM + (wv*2 + jn)*16 + ar] = r * inv;
        }
    }
}

extern "C" void kernel_launch(void* const* d_in, const int* in_sizes, int n_in,
                              void* d_out, int out_size, void* d_ws, size_t ws_size,
                              hipStream_t stream) {
    const float* x        = (const float*)d_in[0];
    const int*   pad_mask = (const int*)d_in[1];
    const float* W_in     = (const float*)d_in[2];
    const float* conv_w   = (const float*)d_in[3];
    const float* conv_b   = (const float*)d_in[4];
    const float* W_x      = (const float*)d_in[5];
    const float* W_dt     = (const float*)d_in[6];
    const float* b_dt     = (const float*)d_in[7];
    const float* A_log    = (const float*)d_in[8];
    const float* Dvec     = (const float*)d_in[9];
    const float* W_out    = (const float*)d_in[10];
    _Float16* ws = (_Float16*)d_ws;

    convert_weights<<<(WS_TOT + 255)/256, 256, 0, stream>>>(W_in, conv_w, W_x, W_out, ws);
    mamba_mfma_kernel<<<NB, 256, 0, stream>>>(x, pad_mask, conv_b, W_dt, b_dt,
                                              A_log, Dvec, ws, (float*)d_out);
}